// Round 10
// baseline (143.448 us; speedup 1.0000x reference)
//
#include <hip/hip_runtime.h>
#include <hip/hip_bf16.h>

// Problem constants
#define B    32
#define P    576     // 24*24 patches
#define D    768
#define K1   17      // K+1 prototypes
#define KFG  16
#define C    200
#define LN_EPS 1e-6f

typedef __attribute__((ext_vector_type(8))) short short8;   // 8 bf16 (4 VGPRs)
typedef __attribute__((ext_vector_type(4))) float f32x4;

__device__ inline unsigned short f2b(float f) {   // fp32 -> bf16 RNE
    union { float f; unsigned u; } x; x.f = f;
    unsigned r = x.u + 0x7FFF + ((x.u >> 16) & 1);
    return (unsigned short)(r >> 16);
}
__device__ inline float b2f(unsigned short u) {   // bf16 -> fp32 exact
    union { unsigned u; float f; } x; x.u = ((unsigned)u) << 16;
    return x.f;
}
// packed fp32x8 -> bf16x8 via v_cvt_pk_bf16_f32
__device__ inline short8 cvt8(float4 a, float4 b) {
    union { unsigned u[4]; short8 s; } r;
    union { __hip_bfloat162 h; unsigned u; } c;
    c.h = __float22bfloat162_rn(make_float2(a.x, a.y)); r.u[0] = c.u;
    c.h = __float22bfloat162_rn(make_float2(a.z, a.w)); r.u[1] = c.u;
    c.h = __float22bfloat162_rn(make_float2(b.x, b.y)); r.u[2] = c.u;
    c.h = __float22bfloat162_rn(make_float2(b.z, b.w)); r.u[3] = c.u;
    return r.s;
}
__device__ inline float sq8(float4 a, float4 b) {
    return a.x*a.x + a.y*a.y + a.z*a.z + a.w*a.w
         + b.x*b.x + b.y*b.y + b.z*b.z + b.w*b.w;
}

// ================= K1: dots (bf16 MFMA, K-split 4) + softmax + MFMA-pool =================
// grid (18 psl, 32 b) x 512 (8 waves). Waves 0-3: tile0 K-quarters; 4-7: tile1.
// 4608 waves (~18/CU). Epilogue (waves 0,1) reduces K-quarters + softmax, parks
// a/P transposed in 1KB bf16 LDS. Pool = second MFMA: v[k][d] = a^T(16x32)*x(32x768),
// A-frag one loop-invariant ds_read_b128, B-frag = L2-hot x re-read. vpart bf16.
__global__ __launch_bounds__(512) void k_front(const float* __restrict__ x,
                                               const float* __restrict__ proto,
                                               float* __restrict__ A_out,
                                               unsigned short* __restrict__ vpart) {
    __shared__ float scL[8 * 64 * 11];        // 22.5 KB [wave][lane][acc0:4|acc1:4|sq0|sq6]
    __shared__ unsigned short asT[16 * 32];   // 1 KB, a^T/P bf16: [k][p_local]
    const int psl = blockIdx.x, b = blockIdx.y;
    const int t = threadIdx.x, wv = t >> 6, lane = t & 63;
    const int n = lane & 15, kq = lane >> 4;
    const int tilesel = wv >> 2, kqt = wv & 3;
    const int p0 = psl * 32 + tilesel * 16;

    const float* arow = x     + ((size_t)(b * P + p0 + n)) * D + kqt * 192 + kq * 8;
    const float* brow = proto + (size_t)n  * D + kqt * 192 + kq * 8;
    const float* brw6 = proto + (size_t)16 * D + kqt * 192 + kq * 8;

    f32x4 acc0 = {0.f, 0.f, 0.f, 0.f};   // protos 0..15, this K-quarter
    f32x4 acc1 = {0.f, 0.f, 0.f, 0.f};   // proto 16 (broadcast B)
    float sq0 = 0.f, sq6 = 0.f;          // psq partials (fp32-exact)

    #pragma unroll
    for (int s = 0; s < 6; ++s) {
        float4 a0 = *(const float4*)(arow + s * 32);
        float4 a1 = *(const float4*)(arow + s * 32 + 4);
        float4 b0 = *(const float4*)(brow + s * 32);
        float4 b1 = *(const float4*)(brow + s * 32 + 4);
        float4 c0 = *(const float4*)(brw6 + s * 32);
        float4 c1 = *(const float4*)(brw6 + s * 32 + 4);
        short8 A  = cvt8(a0, a1);
        short8 Bv = cvt8(b0, b1);
        short8 B6 = cvt8(c0, c1);
        sq0 += sq8(b0, b1);
        sq6 += sq8(c0, c1);
        acc0 = __builtin_amdgcn_mfma_f32_16x16x32_bf16(A, Bv, acc0, 0, 0, 0);
        acc1 = __builtin_amdgcn_mfma_f32_16x16x32_bf16(A, B6, acc1, 0, 0, 0);
    }
    // fold the 4 kq-quads (lanes n, n+16, n+32, n+48 share proto n)
    sq0 += __shfl_xor(sq0, 16, 64); sq0 += __shfl_xor(sq0, 32, 64);
    sq6 += __shfl_xor(sq6, 16, 64); sq6 += __shfl_xor(sq6, 32, 64);

    {
        float* s = scL + (wv * 64 + lane) * 11;
        #pragma unroll
        for (int r = 0; r < 4; ++r) { s[r] = acc0[r]; s[r + 4] = acc1[r]; }
        s[8] = sq0; s[9] = sq6;
    }
    __syncthreads();

    // ---- epilogue: wave 0 -> tile0 (scL 0..3), wave 1 -> tile1 (scL 4..7) ----
    if (wv < 2) {
        float f0[4], f1[4]; float fsq0 = 0.f, fsq6 = 0.f;
        #pragma unroll
        for (int r = 0; r < 4; ++r) { f0[r] = 0.f; f1[r] = 0.f; }
        #pragma unroll
        for (int w = 0; w < 4; ++w) {
            const float* s = scL + ((wv * 4 + w) * 64 + lane) * 11;
            #pragma unroll
            for (int r = 0; r < 4; ++r) { f0[r] += s[r]; f1[r] += s[r + 4]; }
            fsq0 += s[8]; fsq6 += s[9];
        }

        float a_[4], a16[4];
        #pragma unroll
        for (int r = 0; r < 4; ++r) {
            float l0  = 2.f * f0[r] - fsq0;
            float l16 = 2.f * f1[r] - fsq6;
            float mx = l0;
            #pragma unroll
            for (int o = 1; o < 16; o <<= 1) mx = fmaxf(mx, __shfl_xor(mx, o, 64));
            mx = fmaxf(mx, l16);
            float e0  = __expf(l0 - mx);
            float e16 = __expf(l16 - mx);
            float sum = e0;
            #pragma unroll
            for (int o = 1; o < 16; o <<= 1) sum += __shfl_xor(sum, o, 64);
            sum += e16;
            const float inv = 1.f / sum;
            a_[r]  = e0 * inv;
            a16[r] = e16 * inv;
        }

        const int pe = psl * 32 + wv * 16;
        *(float4*)(A_out + ((size_t)b * K1 + n) * P + pe + kq * 4) =
            make_float4(a_[0], a_[1], a_[2], a_[3]);
        if (n == 0)
            *(float4*)(A_out + ((size_t)b * K1 + 16) * P + pe + kq * 4) =
                make_float4(a16[0], a16[1], a16[2], a16[3]);

        const float invP = 1.f / (float)P;
        #pragma unroll
        for (int r = 0; r < 4; ++r)
            asT[n * 32 + wv * 16 + kq * 4 + r] = f2b(a_[r] * invP);   // [k][p_local]
    }
    __syncthreads();

    // ---- pool via MFMA: wave wv owns d-range [wv*96, wv*96+96) ----
    // A-frag (loop-invariant): a^T[k = lane&15][p = kq*8 + j]  (one ds_read_b128)
    short8 Afrag = *(const short8*)(asT + (lane & 15) * 32 + kq * 8);
    const float* xb = x + ((size_t)(b * P + psl * 32)) * D;
    unsigned short* vout = vpart + ((size_t)(psl * B + b) * KFG) * D;

    #pragma unroll
    for (int m6 = 0; m6 < 6; ++m6) {
        const int dcol = wv * 96 + m6 * 16 + n;
        short8 Bfrag;   // B[p = kq*8+j][dcol]: per j, 16 n-lanes cover one 64B line
        #pragma unroll
        for (int j = 0; j < 8; j += 2) {
            float v0 = xb[(size_t)(kq * 8 + j)     * D + dcol];
            float v1 = xb[(size_t)(kq * 8 + j + 1) * D + dcol];
            union { __hip_bfloat162 h; unsigned u; } cc;
            cc.h = __float22bfloat162_rn(make_float2(v0, v1));
            Bfrag[j]     = (short)(cc.u & 0xFFFF);
            Bfrag[j + 1] = (short)(cc.u >> 16);
        }
        f32x4 accv = {0.f, 0.f, 0.f, 0.f};
        accv = __builtin_amdgcn_mfma_f32_16x16x32_bf16(Afrag, Bfrag, accv, 0, 0, 0);
        // C layout: row(k) = kq*4 + r, col(d) = dcol
        #pragma unroll
        for (int r = 0; r < 4; ++r)
            vout[(size_t)(kq * 4 + r) * D + dcol] = f2b(accv[r]);
    }
}

// ================= K2: reduce 18 bf16 p-slices + LayerNorm; write vnorm + vT =================
// grid (16 k, 32 b) x 256; thread owns 3 d's.
__global__ __launch_bounds__(256) void k_ln(const unsigned short* __restrict__ vpart,
                                            const float* __restrict__ gamma,
                                            const float* __restrict__ beta,
                                            float* __restrict__ vnorm_out,
                                            float* __restrict__ vT) {
    const int k = blockIdx.x, b = blockIdx.y, t = threadIdx.x;
    const int lane = t & 63, wv = t >> 6;

    float v[3]; float s1 = 0.f, s2 = 0.f;
    #pragma unroll
    for (int j = 0; j < 3; ++j) {
        const int d = t + j * 256;
        float s = 0.f;
        #pragma unroll
        for (int psl = 0; psl < 18; ++psl)
            s += b2f(vpart[((size_t)(psl * B + b) * KFG + k) * D + d]);
        v[j] = s; s1 += s; s2 += s * s;
    }
    #pragma unroll
    for (int o = 1; o < 64; o <<= 1) {
        s1 += __shfl_xor(s1, o, 64);
        s2 += __shfl_xor(s2, o, 64);
    }
    __shared__ float r1[4], r2[4];
    if (lane == 0) { r1[wv] = s1; r2[wv] = s2; }
    __syncthreads();
    s1 = r1[0] + r1[1] + r1[2] + r1[3];
    s2 = r2[0] + r2[1] + r2[2] + r2[3];

    const float mean = s1 * (1.f / (float)D);
    const float var  = s2 * (1.f / (float)D) - mean * mean;
    const float rs   = rsqrtf(var + LN_EPS);

    #pragma unroll
    for (int j = 0; j < 3; ++j) {
        const int d = t + j * 256;
        float vn = (v[j] - mean) * rs * gamma[d] + beta[d];
        vnorm_out[((size_t)b * KFG + k) * D + d] = vn;
        vT[((size_t)b * D + d) * KFG + k] = vn;   // k-contiguous for K3 s_loads
    }
}

// ================= K3: classifier + bias + agg, fused (fixed uniform s_loads) =================
// grid 64 = (b, class-half) x 512 (8 waves). cq = readfirstlane(t>>7) -> SGPR row
// pointer -> true s_load_dwordx16 (R8's bug: compiler saw t>>7 as divergent).
__global__ __launch_bounds__(512) void k_cls(const float* __restrict__ vT,
                                             const float* __restrict__ W,
                                             const float* __restrict__ bcls,
                                             float* __restrict__ parts_out,
                                             float* __restrict__ agg_out) {
    __shared__ float lp[4 * 128 * KFG];   // 32 KB
    const int b = blockIdx.x >> 1, ch = blockIdx.x & 1;
    const int t = threadIdx.x;
    const int cqv = t >> 7;                                      // for LDS addressing
    const int cq  = __builtin_amdgcn_readfirstlane(cqv);         // wave-uniform -> SGPR
    const int cl  = t & 127;
    const int c   = ch * 100 + (cl < 100 ? cl : 99);             // clamp keeps loads in-bounds

    const float* vt = vT + ((size_t)b * D + cq * 192) * KFG;     // scalar base -> s_loads
    const float* Wp = W + (size_t)(cq * 192) * C + c;

    float acc[KFG];
    #pragma unroll
    for (int k = 0; k < KFG; ++k) acc[k] = 0.f;

    #pragma unroll 4
    for (int i = 0; i < 192; ++i) {
        float wl = Wp[(size_t)i * C];                 // coalesced across lanes
        f32x4 V0 = *(const f32x4*)(vt + i * 16);      // uniform -> s_load_dwordx16
        f32x4 V1 = *(const f32x4*)(vt + i * 16 + 4);
        f32x4 V2 = *(const f32x4*)(vt + i * 16 + 8);
        f32x4 V3 = *(const f32x4*)(vt + i * 16 + 12);
        acc[0]  += V0[0] * wl; acc[1]  += V0[1] * wl; acc[2]  += V0[2] * wl; acc[3]  += V0[3] * wl;
        acc[4]  += V1[0] * wl; acc[5]  += V1[1] * wl; acc[6]  += V1[2] * wl; acc[7]  += V1[3] * wl;
        acc[8]  += V2[0] * wl; acc[9]  += V2[1] * wl; acc[10] += V2[2] * wl; acc[11] += V2[3] * wl;
        acc[12] += V3[0] * wl; acc[13] += V3[1] * wl; acc[14] += V3[2] * wl; acc[15] += V3[3] * wl;
    }
    #pragma unroll
    for (int k = 0; k < KFG; ++k) lp[(cqv * 128 + cl) * KFG + k] = acc[k];
    __syncthreads();

    if (t < 100) {
        const int cw = ch * 100 + t;
        const float bc = bcls[cw];
        float s_agg = 0.f;
        #pragma unroll
        for (int k = 0; k < KFG; ++k) {
            float s = bc + lp[(0 * 128 + t) * KFG + k] + lp[(1 * 128 + t) * KFG + k]
                         + lp[(2 * 128 + t) * KFG + k] + lp[(3 * 128 + t) * KFG + k];
            parts_out[((size_t)b * KFG + k) * C + cw] = s;
            s_agg += s;
        }
        agg_out[(size_t)b * C + cw] = s_agg * (1.f / (float)KFG);
    }
}

extern "C" void kernel_launch(void* const* d_in, const int* in_sizes, int n_in,
                              void* d_out, int out_size, void* d_ws, size_t ws_size,
                              hipStream_t stream) {
    const float* x     = (const float*)d_in[0];   // (32,24,24,768)
    const float* proto = (const float*)d_in[1];   // (17,768)
    const float* gamma = (const float*)d_in[2];   // (768)
    const float* beta  = (const float*)d_in[3];   // (768)
    const float* W     = (const float*)d_in[4];   // (768,200)
    const float* bcls  = (const float*)d_in[5];   // (200)

    float* out = (float*)d_out;
    float* A_out     = out;                       // 32*17*576   = 313344
    float* vnorm_out = out + 313344;              // 32*16*768   = 393216
    float* parts_out = out + 706560;              // 32*16*200   = 102400
    float* agg_out   = out + 808960;              // 32*200      = 6400

    float* ws = (float*)d_ws;
    unsigned short* vpart = (unsigned short*)ws;   // 18*32*16*768 bf16 (3538944 floats)
    float* vT = ws + 3538944;                      // 32*768*16 = 393216

    hipLaunchKernelGGL(k_front, dim3(18, B),  dim3(512), 0, stream, x, proto, A_out, vpart);
    hipLaunchKernelGGL(k_ln,    dim3(KFG, B), dim3(256), 0, stream, vpart, gamma, beta, vnorm_out, vT);
    hipLaunchKernelGGL(k_cls,   dim3(64),     dim3(512), 0, stream, vT, W, bcls, parts_out, agg_out);
}